// Round 3
// baseline (162.485 us; speedup 1.0000x reference)
//
#include <hip/hip_runtime.h>
#include <hip/hip_bf16.h>
#include <math.h>

#define BB 8
#define HH 96
#define WW 96
#define HW 9216
#define BN_EPS 1e-5f

typedef short bf16x8 __attribute__((ext_vector_type(8)));
typedef float f32x4 __attribute__((ext_vector_type(4)));

// ---- workspace layout (bytes) ----
#define OFF_W4   0
#define SZ_W4    (BB*9*HW*16)          // float4 per (b,k,pixel)
#define OFF_XT   (OFF_W4 + SZ_W4)
#define SZ_XT    (BB*HW*64*2)          // bf16 x transposed (B,H,W,C)
#define OFF_XY   (OFF_XT + SZ_XT)
#define SZ_XY    (BB*9*HW*4)           // packed clamped tap indices
#define OFF_WB   (OFF_XY + SZ_XY)
#define SZ_WB    (64*576*2)            // wB[o][ck] bf16, ck = k*64+c
#define OFF_WALL (OFF_WB + SZ_WB)
#define SZ_WALL  (576*27*4)            // wAll[c*9+kk][27] f32

// ---------------- prep: weight transposes ----------------
__global__ __launch_bounds__(256) void prep_kernel(
    const float* __restrict__ weight, const float* __restrict__ offw,
    const float* __restrict__ modw,
    __hip_bfloat16* __restrict__ wB, float* __restrict__ wAll) {
  int tid = blockIdx.x * 256 + threadIdx.x;
  if (tid < 64 * 576) {
    int o = tid / 576, ck = tid % 576;
    int k = ck >> 6, c = ck & 63;                // ck = k*64 + c
    wB[tid] = __float2bfloat16(weight[o * 576 + c * 9 + k]);
  }
  int t2 = tid - 64 * 576;
  if (t2 >= 0 && t2 < 576 * 27) {
    int ck2 = t2 / 27, oc = t2 % 27;             // ck2 = c*9 + kk
    wAll[t2] = (oc < 18) ? offw[oc * 576 + ck2] : modw[(oc - 18) * 576 + ck2];
  }
}

// ---------------- LDS-tiled transpose x -> (B,H,W,C) bf16 ----------------
__global__ __launch_bounds__(256) void transpose_x_kernel(
    const float* __restrict__ x, __hip_bfloat16* __restrict__ xT) {
  __shared__ float tile[64][65];
  int tid = threadIdx.x;
  int b = blockIdx.x / 144, hwb = (blockIdx.x % 144) * 64;
  int col = tid & 63, g = tid >> 6;
#pragma unroll
  for (int it = 0; it < 16; ++it) {
    int c = it * 4 + g;
    tile[c][col] = x[(b * 64 + c) * HW + hwb + col];   // coalesced 256B
  }
  __syncthreads();
#pragma unroll
  for (int it = 0; it < 16; ++it) {
    int p = it * 4 + g;
    xT[(size_t)(b * HW + hwb + p) * 64 + col] = __float2bfloat16(tile[col][p]);
  }
}

// ---------------- offset/mod convs (channel-split x4) + fold ----------------
__global__ __launch_bounds__(256) void conv_coords_kernel(
    const float* __restrict__ x, const float* __restrict__ wAll,
    const float* __restrict__ offb, const float* __restrict__ modb,
    float4* __restrict__ w4, unsigned* __restrict__ xy) {
  __shared__ float s_r[4][64][29];
  int tid = threadIdx.x;
  int pxl = tid & 63;
  int cg = __builtin_amdgcn_readfirstlane(tid >> 6);   // wave-uniform -> s_loads
  int pix = blockIdx.x * 64 + pxl;
  int b = pix / HW, hw = pix - b * HW;
  int h = hw / WW, w = hw - h * WW;

  bool vy[3], vx[3];
#pragma unroll
  for (int i = 0; i < 3; i++) {
    int y = h + i - 1;  vy[i] = (y >= 0) && (y < HH);
    int xx = w + i - 1; vx[i] = (xx >= 0) && (xx < WW);
  }

  float acc[27];
#pragma unroll
  for (int i = 0; i < 27; i++) acc[i] = 0.f;

  const float* xb = x + b * 64 * HW;
#pragma unroll 2
  for (int ci = 0; ci < 16; ++ci) {
    int c = cg * 16 + ci;
    const float* xp = xb + c * HW;
    float xv[9];
#pragma unroll
    for (int ky = 0; ky < 3; ky++)
#pragma unroll
      for (int kx = 0; kx < 3; kx++) {
        int y = h + ky - 1, xx = w + kx - 1;
        xv[ky * 3 + kx] = (vy[ky] && vx[kx]) ? xp[y * WW + xx] : 0.f;
      }
    const float* wp = wAll + c * 243;                  // uniform -> SMEM
#pragma unroll
    for (int kk = 0; kk < 9; kk++) {
      float xvv = xv[kk];
#pragma unroll
      for (int oc = 0; oc < 27; oc++)
        acc[oc] += xvv * wp[kk * 27 + oc];
    }
  }
#pragma unroll
  for (int i = 0; i < 27; i++) s_r[cg][pxl][i] = acc[i];
  __syncthreads();

  for (int it = tid; it < 576; it += 256) {
    int px = it & 63, k = it >> 6;
    int pix2 = blockIdx.x * 64 + px;
    int b2 = pix2 / HW, hw2 = pix2 - b2 * HW;
    int h2 = hw2 / WW, w2 = hw2 - h2 * WW;
    int ky = k / 3, kx = k - ky * 3;

    float a0 = s_r[0][px][2 * k] + s_r[1][px][2 * k] + s_r[2][px][2 * k] + s_r[3][px][2 * k];
    float a1 = s_r[0][px][2 * k + 1] + s_r[1][px][2 * k + 1] + s_r[2][px][2 * k + 1] + s_r[3][px][2 * k + 1];
    float a2 = s_r[0][px][18 + k] + s_r[1][px][18 + k] + s_r[2][px][18 + k] + s_r[3][px][18 + k];

    float offy = a0 + offb[2 * k];
    float offx = a1 + offb[2 * k + 1];
    float mod = 2.f / (1.f + __expf(-(a2 + modb[k])));

    float py = (float)(h2 - 1 + ky) + offy;
    float px_ = (float)(w2 - 1 + kx) + offx;
    float y0f = floorf(py), x0f = floorf(px_);
    float dy = py - y0f, dx = px_ - x0f;
    int y0 = (int)y0f, x0 = (int)x0f;
    int y1 = y0 + 1, x1 = x0 + 1;
    bool vy0 = (y0 >= 0) && (y0 < HH), vy1 = (y1 >= 0) && (y1 < HH);
    bool vx0 = (x0 >= 0) && (x0 < WW), vx1 = (x1 >= 0) && (x1 < WW);
    float w00 = (vy0 && vx0) ? (1.f - dy) * (1.f - dx) * mod : 0.f;
    float w01 = (vy0 && vx1) ? (1.f - dy) * dx * mod : 0.f;
    float w10 = (vy1 && vx0) ? dy * (1.f - dx) * mod : 0.f;
    float w11 = (vy1 && vx1) ? dy * dx * mod : 0.f;
    int y0c = min(max(y0, 0), HH - 1), y1c = min(max(y1, 0), HH - 1);
    int x0c = min(max(x0, 0), WW - 1), x1c = min(max(x1, 0), WW - 1);
    unsigned pk = (unsigned)y0c | ((unsigned)y1c << 8) |
                  ((unsigned)x0c << 16) | ((unsigned)x1c << 24);
    int idx = (b2 * 9 + k) * HW + hw2;
    w4[idx] = make_float4(w00, w01, w10, w11);
    xy[idx] = pk;
  }
}

// ---------------- fused deformable sample + MFMA GEMM + BN + ReLU ----------------
// 16 pixels/block, LDS 18.7 KB -> 8 blocks/CU; VGPR<=64 -> up to 32 waves/CU.
__global__ __launch_bounds__(256, 8) void dcn_main_kernel(
    const __hip_bfloat16* __restrict__ xT,
    const float4* __restrict__ w4, const unsigned* __restrict__ xy,
    const __hip_bfloat16* __restrict__ wB,
    const float* __restrict__ bias, const float* __restrict__ gamma,
    const float* __restrict__ beta, const float* __restrict__ mean,
    const float* __restrict__ var,
    float* __restrict__ out) {
  __shared__ __attribute__((aligned(16))) __hip_bfloat16 s_A[16 * 584];
  float* o_lds = (float*)s_A;                          // aliased after barrier

  int tid = threadIdx.x;
  int lane = tid & 63;
  int wv = __builtin_amdgcn_readfirstlane(tid >> 6);

  int bi = blockIdx.x;                                 // 8 * 576 blocks
  int b = bi / 576, t = bi - b * 576;
  int h = t / 6, w0 = (t - h * 6) * 16;
  int hwrow = h * WW + w0;

  // ---- phase A: deformable sampling, lane = channel, 4 pixels/wave ----
  const __hip_bfloat16* xb = xT + (size_t)b * HW * 64;
#pragma unroll
  for (int p = 0; p < 4; ++p) {
    int pl = wv * 4 + p;
    int hw = hwrow + pl;
#pragma unroll
    for (int k = 0; k < 9; ++k) {
      int idx = (b * 9 + k) * HW + hw;                 // wave-uniform -> s_load
      float4 wj = w4[idx];
      unsigned pk = xy[idx];
      int y0 = pk & 255, y1 = (pk >> 8) & 255, x0 = (pk >> 16) & 255, x1 = pk >> 24;
      float v00 = __bfloat162float(xb[(y0 * WW + x0) * 64 + lane]);
      float v01 = __bfloat162float(xb[(y0 * WW + x1) * 64 + lane]);
      float v10 = __bfloat162float(xb[(y1 * WW + x0) * 64 + lane]);
      float v11 = __bfloat162float(xb[(y1 * WW + x1) * 64 + lane]);
      float s = wj.x * v00 + wj.y * v01 + wj.z * v10 + wj.w * v11;
      s_A[pl * 584 + k * 64 + lane] = __float2bfloat16(s);
    }
  }
  __syncthreads();

  // ---- phase B: [16 x 576] x [576 x 64] bf16 MFMA, wave -> 16 out-channels ----
  int r = lane & 15, g = lane >> 4;
  const __hip_bfloat16* arow = s_A + r * 584 + g * 8;
  const __hip_bfloat16* bp = wB + (wv * 16 + r) * 576 + g * 8;
  f32x4 accA = {0.f, 0.f, 0.f, 0.f}, accB = {0.f, 0.f, 0.f, 0.f};
#pragma unroll 3
  for (int s = 0; s < 18; s += 2) {
    bf16x8 a0 = *(const bf16x8*)(arow + s * 32);
    bf16x8 b0 = *(const bf16x8*)(bp + s * 32);
    bf16x8 a1 = *(const bf16x8*)(arow + s * 32 + 32);
    bf16x8 b1 = *(const bf16x8*)(bp + s * 32 + 32);
    accA = __builtin_amdgcn_mfma_f32_16x16x32_bf16(a0, b0, accA, 0, 0, 0);
    accB = __builtin_amdgcn_mfma_f32_16x16x32_bf16(a1, b1, accB, 0, 0, 0);
  }

  // ---- epilogue: bias + BN + ReLU, LDS transpose, coalesced store ----
  int o = wv * 16 + r;                                 // this lane's out channel
  float bs = bias[o] - mean[o];
  float inv = gamma[o] * rsqrtf(var[o] + BN_EPS);
  float bt = beta[o];
  __syncthreads();                                     // all s_A reads done
#pragma unroll
  for (int j = 0; j < 4; ++j) {
    int px = g * 4 + j;                                // C row = (lane>>4)*4+j
    o_lds[o * 20 + px] = fmaxf((accA[j] + accB[j] + bs) * inv + bt, 0.f);
  }
  __syncthreads();

  int oo = tid >> 2, q = tid & 3;
  float4 u = *(const float4*)&o_lds[oo * 20 + q * 4];
  *(float4*)(out + (size_t)(b * 64 + oo) * HW + hwrow + q * 4) = u;
}

extern "C" void kernel_launch(void* const* d_in, const int* in_sizes, int n_in,
                              void* d_out, int out_size, void* d_ws, size_t ws_size,
                              hipStream_t stream) {
  const float* x      = (const float*)d_in[0];
  const float* offw   = (const float*)d_in[1];
  const float* offb   = (const float*)d_in[2];
  const float* modw   = (const float*)d_in[3];
  const float* modb   = (const float*)d_in[4];
  const float* weight = (const float*)d_in[5];
  const float* bias   = (const float*)d_in[6];
  const float* gamma  = (const float*)d_in[7];
  const float* beta   = (const float*)d_in[8];
  const float* mean   = (const float*)d_in[9];
  const float* var    = (const float*)d_in[10];

  char* ws = (char*)d_ws;
  float4*         w4    = (float4*)(ws + OFF_W4);
  __hip_bfloat16* xT    = (__hip_bfloat16*)(ws + OFF_XT);
  unsigned*       xybuf = (unsigned*)(ws + OFF_XY);
  __hip_bfloat16* wB    = (__hip_bfloat16*)(ws + OFF_WB);
  float*          wAll  = (float*)(ws + OFF_WALL);

  prep_kernel<<<205, 256, 0, stream>>>(weight, offw, modw, wB, wAll);
  transpose_x_kernel<<<1152, 256, 0, stream>>>(x, xT);
  conv_coords_kernel<<<1152, 256, 0, stream>>>(x, wAll, offb, modb, w4, xybuf);
  dcn_main_kernel<<<4608, 256, 0, stream>>>(xT, w4, xybuf, wB, bias, gamma, beta,
                                            mean, var, (float*)d_out);
}

// Round 4
// 119.801 us; speedup vs baseline: 1.3563x; 1.3563x over previous
//
#include <hip/hip_runtime.h>
#include <hip/hip_bf16.h>
#include <hip/hip_fp16.h>
#include <math.h>

#define BB 8
#define HH 96
#define WW 96
#define HW 9216
#define BN_EPS 1e-5f

typedef _Float16 f16x8 __attribute__((ext_vector_type(8)));
typedef float f32x4 __attribute__((ext_vector_type(4)));

// ---- workspace layout (bytes) ----
#define OFF_W4   0
#define SZ_W4    (BB*9*HW*16)          // float4 per (b,k,pixel)
#define OFF_XT   (OFF_W4 + SZ_W4)
#define SZ_XT    (BB*HW*64*2)          // fp16 x transposed (B,H,W,C)
#define OFF_XY   (OFF_XT + SZ_XT)
#define SZ_XY    (BB*9*HW*4)           // packed clamped tap indices
#define OFF_WB   (OFF_XY + SZ_XY)
#define SZ_WB    (64*576*2)            // wB[o][k*64+c] fp16 (main conv)
#define OFF_WO   (OFF_WB + SZ_WB)
#define SZ_WO    (32*576*2)            // wOff[oc][kk*64+c] fp16 (offset+mod conv, 27 used)

// ---------------- prep: weight transposes ----------------
__global__ __launch_bounds__(256) void prep_kernel(
    const float* __restrict__ weight, const float* __restrict__ offw,
    const float* __restrict__ modw,
    _Float16* __restrict__ wB, _Float16* __restrict__ wOff) {
  int tid = blockIdx.x * 256 + threadIdx.x;
  if (tid < 64 * 576) {
    int o = tid / 576, ck = tid % 576;
    int k = ck >> 6, c = ck & 63;                // ck = k*64 + c
    wB[tid] = (_Float16)weight[o * 576 + c * 9 + k];
  }
  int t2 = tid - 64 * 576;
  if (t2 >= 0 && t2 < 32 * 576) {
    int oc = t2 / 576, kcol = t2 % 576;
    int kk = kcol >> 6, c = kcol & 63;           // kcol = kk*64 + c
    float v = 0.f;
    if (oc < 18)      v = offw[(oc * 64 + c) * 9 + kk];
    else if (oc < 27) v = modw[((oc - 18) * 64 + c) * 9 + kk];
    wOff[t2] = (_Float16)v;
  }
}

// ---------------- LDS-tiled transpose x -> (B,H,W,C) fp16 ----------------
__global__ __launch_bounds__(256) void transpose_x_kernel(
    const float* __restrict__ x, _Float16* __restrict__ xT) {
  __shared__ float tile[64][65];
  int tid = threadIdx.x;
  int b = blockIdx.x / 144, hwb = (blockIdx.x % 144) * 64;
  int col = tid & 63, g = tid >> 6;
#pragma unroll
  for (int it = 0; it < 16; ++it) {
    int c = it * 4 + g;
    tile[c][col] = x[(b * 64 + c) * HW + hwb + col];   // coalesced 256B
  }
  __syncthreads();
#pragma unroll
  for (int it = 0; it < 16; ++it) {
    int p = it * 4 + g;
    xT[(size_t)(b * HW + hwb + p) * 64 + col] = (_Float16)tile[col][p];
  }
}

// ---------------- offset/mod conv via MFMA + fold into sample weights ----------------
// 32 px/block. A[32][576] from fixed 3x3 neighborhood (kcol = kk*64+c), B = wOff.
__global__ __launch_bounds__(256, 8) void conv_offsets_kernel(
    const _Float16* __restrict__ xTh, const _Float16* __restrict__ wOff,
    const float* __restrict__ offb, const float* __restrict__ modb,
    float4* __restrict__ w4, unsigned* __restrict__ xy) {
  __shared__ __attribute__((aligned(16))) _Float16 sN[3 * 34 * 70]; // stride-70 pad
  __shared__ float o_off[32 * 33];

  int tid = threadIdx.x;
  int lane = tid & 63;
  int wv = __builtin_amdgcn_readfirstlane(tid >> 6);

  int bi = blockIdx.x;                                  // 8 * 96 * 3
  int b = bi / 288, rem = bi % 288;
  int h = rem / 3, w0 = (rem % 3) * 32;

  // ---- stage 3 rows x 34 cols x 64 ch, zero-padded OOB ----
  const _Float16* xb = xTh + (size_t)b * HW * 64;
  for (int p = wv; p < 102; p += 4) {                   // wave-uniform (row,col)
    int row = p / 34, col = p - row * 34;
    int y = h + row - 1, xx = w0 + col - 1;
    _Float16 v = (_Float16)0.f;
    if ((y >= 0) && (y < HH) && (xx >= 0) && (xx < WW))
      v = xb[(size_t)(y * WW + xx) * 64 + lane];
    sN[(row * 34 + col) * 70 + lane] = v;
  }
  __syncthreads();

  // ---- MFMA: C[32 px][32 oc], wave = (m-tile, n-tile) quadrant ----
  int r = lane & 15, g = lane >> 4;
  int mt = wv >> 1, nt = wv & 1;
  int px = mt * 16 + r;
  const _Float16* bp = wOff + (nt * 16 + r) * 576 + g * 8;
  f32x4 acc = {0.f, 0.f, 0.f, 0.f};
#pragma unroll
  for (int s = 0; s < 18; ++s) {
    int kk = s >> 1, ky = kk / 3, kx = kk - ky * 3;
    f16x8 a = *(const f16x8*)&sN[(ky * 34 + px + kx) * 70 + (s & 1) * 32 + g * 8];
    f16x8 bb = *(const f16x8*)(bp + s * 32);
    acc = __builtin_amdgcn_mfma_f32_16x16x32_f16(a, bb, acc, 0, 0, 0);
  }
#pragma unroll
  for (int j = 0; j < 4; ++j)
    o_off[(mt * 16 + g * 4 + j) * 33 + nt * 16 + r] = acc[j];
  __syncthreads();

  // ---- fold: sigmoid + bilinear weights + clamped taps, write w4/xy ----
  for (int it = tid; it < 288; it += 256) {
    int pxx = it & 31, k = it >> 5;
    int ky = k / 3, kx = k - ky * 3;
    int w = w0 + pxx;

    float offy = o_off[pxx * 33 + 2 * k]     + offb[2 * k];
    float offx = o_off[pxx * 33 + 2 * k + 1] + offb[2 * k + 1];
    float mod  = 2.f / (1.f + __expf(-(o_off[pxx * 33 + 18 + k] + modb[k])));

    float py  = (float)(h - 1 + ky) + offy;
    float px_ = (float)(w - 1 + kx) + offx;
    float y0f = floorf(py), x0f = floorf(px_);
    float dy = py - y0f, dx = px_ - x0f;
    int y0 = (int)y0f, x0 = (int)x0f;
    int y1 = y0 + 1, x1 = x0 + 1;
    bool vy0 = (y0 >= 0) && (y0 < HH), vy1 = (y1 >= 0) && (y1 < HH);
    bool vx0 = (x0 >= 0) && (x0 < WW), vx1 = (x1 >= 0) && (x1 < WW);
    float w00 = (vy0 && vx0) ? (1.f - dy) * (1.f - dx) * mod : 0.f;
    float w01 = (vy0 && vx1) ? (1.f - dy) * dx * mod : 0.f;
    float w10 = (vy1 && vx0) ? dy * (1.f - dx) * mod : 0.f;
    float w11 = (vy1 && vx1) ? dy * dx * mod : 0.f;
    int y0c = min(max(y0, 0), HH - 1), y1c = min(max(y1, 0), HH - 1);
    int x0c = min(max(x0, 0), WW - 1), x1c = min(max(x1, 0), WW - 1);
    unsigned pk = (unsigned)y0c | ((unsigned)y1c << 8) |
                  ((unsigned)x0c << 16) | ((unsigned)x1c << 24);
    int idx = (b * 9 + k) * HW + h * WW + w;
    w4[idx] = make_float4(w00, w01, w10, w11);
    xy[idx] = pk;
  }
}

// ---------------- fused deformable sample + MFMA GEMM + BN + ReLU ----------------
// 16 pixels/block, LDS 18.7 KB -> 8 blocks/CU; VGPR<=64 -> up to 32 waves/CU.
__global__ __launch_bounds__(256, 8) void dcn_main_kernel(
    const _Float16* __restrict__ xT,
    const float4* __restrict__ w4, const unsigned* __restrict__ xy,
    const _Float16* __restrict__ wB,
    const float* __restrict__ bias, const float* __restrict__ gamma,
    const float* __restrict__ beta, const float* __restrict__ mean,
    const float* __restrict__ var,
    float* __restrict__ out) {
  __shared__ __attribute__((aligned(16))) _Float16 s_A[16 * 584];
  float* o_lds = (float*)s_A;                          // aliased after barrier

  int tid = threadIdx.x;
  int lane = tid & 63;
  int wv = __builtin_amdgcn_readfirstlane(tid >> 6);

  int bi = blockIdx.x;                                 // 8 * 576 blocks
  int b = bi / 576, t = bi - b * 576;
  int h = t / 6, w0 = (t - h * 6) * 16;
  int hwrow = h * WW + w0;

  // ---- phase A: deformable sampling, lane = channel, 4 pixels/wave ----
  const _Float16* xb = xT + (size_t)b * HW * 64;
#pragma unroll
  for (int p = 0; p < 4; ++p) {
    int pl = wv * 4 + p;
    int hw = hwrow + pl;
#pragma unroll
    for (int k = 0; k < 9; ++k) {
      int idx = (b * 9 + k) * HW + hw;                 // wave-uniform -> s_load
      float4 wj = w4[idx];
      unsigned pk = xy[idx];
      int y0 = pk & 255, y1 = (pk >> 8) & 255, x0 = (pk >> 16) & 255, x1 = pk >> 24;
      float v00 = (float)xb[(y0 * WW + x0) * 64 + lane];
      float v01 = (float)xb[(y0 * WW + x1) * 64 + lane];
      float v10 = (float)xb[(y1 * WW + x0) * 64 + lane];
      float v11 = (float)xb[(y1 * WW + x1) * 64 + lane];
      float s = wj.x * v00 + wj.y * v01 + wj.z * v10 + wj.w * v11;
      s_A[pl * 584 + k * 64 + lane] = (_Float16)s;
    }
  }
  __syncthreads();

  // ---- phase B: [16 x 576] x [576 x 64] fp16 MFMA, wave -> 16 out-channels ----
  int r = lane & 15, g = lane >> 4;
  const _Float16* arow = s_A + r * 584 + g * 8;
  const _Float16* bp = wB + (wv * 16 + r) * 576 + g * 8;
  f32x4 accA = {0.f, 0.f, 0.f, 0.f}, accB = {0.f, 0.f, 0.f, 0.f};
#pragma unroll 3
  for (int s = 0; s < 18; s += 2) {
    f16x8 a0 = *(const f16x8*)(arow + s * 32);
    f16x8 b0 = *(const f16x8*)(bp + s * 32);
    f16x8 a1 = *(const f16x8*)(arow + s * 32 + 32);
    f16x8 b1 = *(const f16x8*)(bp + s * 32 + 32);
    accA = __builtin_amdgcn_mfma_f32_16x16x32_f16(a0, b0, accA, 0, 0, 0);
    accB = __builtin_amdgcn_mfma_f32_16x16x32_f16(a1, b1, accB, 0, 0, 0);
  }

  // ---- epilogue: bias + BN + ReLU, LDS transpose, coalesced store ----
  int o = wv * 16 + r;                                 // this lane's out channel
  float bs = bias[o] - mean[o];
  float inv = gamma[o] * rsqrtf(var[o] + BN_EPS);
  float bt = beta[o];
  __syncthreads();                                     // all s_A reads done
#pragma unroll
  for (int j = 0; j < 4; ++j) {
    int px = g * 4 + j;                                // C row = (lane>>4)*4+j
    o_lds[o * 20 + px] = fmaxf((accA[j] + accB[j] + bs) * inv + bt, 0.f);
  }
  __syncthreads();

  int oo = tid >> 2, q = tid & 3;
  float4 u = *(const float4*)&o_lds[oo * 20 + q * 4];
  *(float4*)(out + (size_t)(b * 64 + oo) * HW + hwrow + q * 4) = u;
}

extern "C" void kernel_launch(void* const* d_in, const int* in_sizes, int n_in,
                              void* d_out, int out_size, void* d_ws, size_t ws_size,
                              hipStream_t stream) {
  const float* x      = (const float*)d_in[0];
  const float* offw   = (const float*)d_in[1];
  const float* offb   = (const float*)d_in[2];
  const float* modw   = (const float*)d_in[3];
  const float* modb   = (const float*)d_in[4];
  const float* weight = (const float*)d_in[5];
  const float* bias   = (const float*)d_in[6];
  const float* gamma  = (const float*)d_in[7];
  const float* beta   = (const float*)d_in[8];
  const float* mean   = (const float*)d_in[9];
  const float* var    = (const float*)d_in[10];

  char* ws = (char*)d_ws;
  float4*    w4    = (float4*)(ws + OFF_W4);
  _Float16*  xTh   = (_Float16*)(ws + OFF_XT);
  unsigned*  xybuf = (unsigned*)(ws + OFF_XY);
  _Float16*  wB    = (_Float16*)(ws + OFF_WB);
  _Float16*  wOff  = (_Float16*)(ws + OFF_WO);

  prep_kernel<<<216, 256, 0, stream>>>(weight, offw, modw, wB, wOff);
  transpose_x_kernel<<<1152, 256, 0, stream>>>(x, xTh);
  conv_offsets_kernel<<<2304, 256, 0, stream>>>(xTh, wOff, offb, modb, w4, xybuf);
  dcn_main_kernel<<<4608, 256, 0, stream>>>(xTh, w4, xybuf, wB, bias, gamma, beta,
                                            mean, var, (float*)d_out);
}

// Round 5
// 114.061 us; speedup vs baseline: 1.4245x; 1.0503x over previous
//
#include <hip/hip_runtime.h>
#include <hip/hip_bf16.h>
#include <hip/hip_fp16.h>
#include <math.h>

#define BB 8
#define HH 96
#define WW 96
#define HW 9216
#define BN_EPS 1e-5f

typedef _Float16 f16x8 __attribute__((ext_vector_type(8)));
typedef float f32x4 __attribute__((ext_vector_type(4)));

// ---- workspace layout (bytes) ----
#define OFF_W4   0
#define SZ_W4    (BB*9*HW*16)          // float4 per (b,k,pixel)
#define OFF_XT   (OFF_W4 + SZ_W4)
#define SZ_XT    (BB*HW*64*2)          // fp16 x transposed (B,H,W,C)
#define OFF_XY   (OFF_XT + SZ_XT)
#define SZ_XY    (BB*9*HW*4)           // packed clamped tap indices
#define OFF_WB   (OFF_XY + SZ_XY)
#define SZ_WB    (64*576*2)            // wB[o][k*64+c] fp16 (main conv)
#define OFF_WO   (OFF_WB + SZ_WB)
#define SZ_WO    (32*576*2)            // wOff[oc][kk*64+c] fp16 (offset+mod conv, 27 used)

// ---------------- prep: weight transposes ----------------
__global__ __launch_bounds__(256) void prep_kernel(
    const float* __restrict__ weight, const float* __restrict__ offw,
    const float* __restrict__ modw,
    _Float16* __restrict__ wB, _Float16* __restrict__ wOff) {
  int tid = blockIdx.x * 256 + threadIdx.x;
  if (tid < 64 * 576) {
    int o = tid / 576, ck = tid % 576;
    int k = ck >> 6, c = ck & 63;                // ck = k*64 + c
    wB[tid] = (_Float16)weight[o * 576 + c * 9 + k];
  }
  int t2 = tid - 64 * 576;
  if (t2 >= 0 && t2 < 32 * 576) {
    int oc = t2 / 576, kcol = t2 % 576;
    int kk = kcol >> 6, c = kcol & 63;           // kcol = kk*64 + c
    float v = 0.f;
    if (oc < 18)      v = offw[(oc * 64 + c) * 9 + kk];
    else if (oc < 27) v = modw[((oc - 18) * 64 + c) * 9 + kk];
    wOff[t2] = (_Float16)v;
  }
}

// ---------------- LDS-tiled transpose x -> (B,H,W,C) fp16 ----------------
__global__ __launch_bounds__(256) void transpose_x_kernel(
    const float* __restrict__ x, _Float16* __restrict__ xT) {
  __shared__ float tile[64][65];
  int tid = threadIdx.x;
  int b = blockIdx.x / 144, hwb = (blockIdx.x % 144) * 64;
  int col = tid & 63, g = tid >> 6;
#pragma unroll
  for (int it = 0; it < 16; ++it) {
    int c = it * 4 + g;
    tile[c][col] = x[(b * 64 + c) * HW + hwb + col];   // coalesced 256B
  }
  __syncthreads();
#pragma unroll
  for (int it = 0; it < 16; ++it) {
    int p = it * 4 + g;
    xT[(size_t)(b * HW + hwb + p) * 64 + col] = (_Float16)tile[col][p];
  }
}

// ---------------- offset/mod conv via MFMA + fold into sample weights ----------------
// 32 px/block. A[32][576] from fixed 3x3 neighborhood (kcol = kk*64+c), B = wOff.
__global__ __launch_bounds__(256, 8) void conv_offsets_kernel(
    const _Float16* __restrict__ xTh, const _Float16* __restrict__ wOff,
    const float* __restrict__ offb, const float* __restrict__ modb,
    float4* __restrict__ w4, unsigned* __restrict__ xy) {
  __shared__ __attribute__((aligned(16))) _Float16 sN[3 * 34 * 70]; // stride-70 pad
  __shared__ float o_off[32 * 33];

  int tid = threadIdx.x;
  int lane = tid & 63;
  int wv = __builtin_amdgcn_readfirstlane(tid >> 6);

  int bi = blockIdx.x;                                  // 8 * 96 * 3
  int b = bi / 288, rem = bi % 288;
  int h = rem / 3, w0 = (rem % 3) * 32;

  // ---- stage 3 rows x 34 cols x 64 ch, zero-padded OOB ----
  const _Float16* xb = xTh + (size_t)b * HW * 64;
  for (int p = wv; p < 102; p += 4) {                   // wave-uniform (row,col)
    int row = p / 34, col = p - row * 34;
    int y = h + row - 1, xx = w0 + col - 1;
    _Float16 v = (_Float16)0.f;
    if ((y >= 0) && (y < HH) && (xx >= 0) && (xx < WW))
      v = xb[(size_t)(y * WW + xx) * 64 + lane];
    sN[(row * 34 + col) * 70 + lane] = v;
  }
  __syncthreads();

  // ---- MFMA: C[32 px][32 oc], wave = (m-tile, n-tile) quadrant ----
  int r = lane & 15, g = lane >> 4;
  int mt = wv >> 1, nt = wv & 1;
  int px = mt * 16 + r;
  const _Float16* bp = wOff + (nt * 16 + r) * 576 + g * 8;
  f32x4 acc = {0.f, 0.f, 0.f, 0.f};
#pragma unroll
  for (int s = 0; s < 18; ++s) {
    int kk = s >> 1, ky = kk / 3, kx = kk - ky * 3;
    f16x8 a = *(const f16x8*)&sN[(ky * 34 + px + kx) * 70 + (s & 1) * 32 + g * 8];
    f16x8 bb = *(const f16x8*)(bp + s * 32);
    acc = __builtin_amdgcn_mfma_f32_16x16x32_f16(a, bb, acc, 0, 0, 0);
  }
#pragma unroll
  for (int j = 0; j < 4; ++j)
    o_off[(mt * 16 + g * 4 + j) * 33 + nt * 16 + r] = acc[j];
  __syncthreads();

  // ---- fold: sigmoid + bilinear weights + clamped taps, write w4/xy ----
  for (int it = tid; it < 288; it += 256) {
    int pxx = it & 31, k = it >> 5;
    int ky = k / 3, kx = k - ky * 3;
    int w = w0 + pxx;

    float offy = o_off[pxx * 33 + 2 * k]     + offb[2 * k];
    float offx = o_off[pxx * 33 + 2 * k + 1] + offb[2 * k + 1];
    float mod  = 2.f / (1.f + __expf(-(o_off[pxx * 33 + 18 + k] + modb[k])));

    float py  = (float)(h - 1 + ky) + offy;
    float px_ = (float)(w - 1 + kx) + offx;
    float y0f = floorf(py), x0f = floorf(px_);
    float dy = py - y0f, dx = px_ - x0f;
    int y0 = (int)y0f, x0 = (int)x0f;
    int y1 = y0 + 1, x1 = x0 + 1;
    bool vy0 = (y0 >= 0) && (y0 < HH), vy1 = (y1 >= 0) && (y1 < HH);
    bool vx0 = (x0 >= 0) && (x0 < WW), vx1 = (x1 >= 0) && (x1 < WW);
    float w00 = (vy0 && vx0) ? (1.f - dy) * (1.f - dx) * mod : 0.f;
    float w01 = (vy0 && vx1) ? (1.f - dy) * dx * mod : 0.f;
    float w10 = (vy1 && vx0) ? dy * (1.f - dx) * mod : 0.f;
    float w11 = (vy1 && vx1) ? dy * dx * mod : 0.f;
    int y0c = min(max(y0, 0), HH - 1), y1c = min(max(y1, 0), HH - 1);
    int x0c = min(max(x0, 0), WW - 1), x1c = min(max(x1, 0), WW - 1);
    unsigned pk = (unsigned)y0c | ((unsigned)y1c << 8) |
                  ((unsigned)x0c << 16) | ((unsigned)x1c << 24);
    int idx = (b * 9 + k) * HW + h * WW + w;
    w4[idx] = make_float4(w00, w01, w10, w11);
    xy[idx] = pk;
  }
}

// ---------------- fused deformable sample + MFMA GEMM + BN + ReLU ----------------
// 16 pixels/block. Phase A batches all 36 tap loads per pixel for deep MLP.
__global__ __launch_bounds__(256, 6) void dcn_main_kernel(
    const _Float16* __restrict__ xT,
    const float4* __restrict__ w4, const unsigned* __restrict__ xy,
    const _Float16* __restrict__ wB,
    const float* __restrict__ bias, const float* __restrict__ gamma,
    const float* __restrict__ beta, const float* __restrict__ mean,
    const float* __restrict__ var,
    float* __restrict__ out) {
  __shared__ __attribute__((aligned(16))) _Float16 s_A[16 * 584];
  float* o_lds = (float*)s_A;                          // aliased after barrier

  int tid = threadIdx.x;
  int lane = tid & 63;
  int wv = __builtin_amdgcn_readfirstlane(tid >> 6);

  int bi = blockIdx.x;                                 // 8 * 576 blocks
  int b = bi / 576, t = bi - b * 576;
  int h = t / 6, w0 = (t - h * 6) * 16;
  int hwrow = h * WW + w0;

  // ---- phase A: deformable sampling, lane = channel, 4 pixels/wave ----
  const _Float16* xb = xT + (size_t)b * HW * 64;
#pragma unroll
  for (int p = 0; p < 4; ++p) {
    int pl = wv * 4 + p;
    int hw = hwrow + pl;

    // (a) all 9 per-k scalar packets issued together
    float4 wj[9]; unsigned pk[9];
#pragma unroll
    for (int k = 0; k < 9; ++k) {
      int idx = (b * 9 + k) * HW + hw;                 // wave-uniform -> s_load
      wj[k] = w4[idx];
      pk[k] = xy[idx];
    }

    // (b) all 36 tap gathers issued back-to-back into registers
    _Float16 v[36];
#pragma unroll
    for (int k = 0; k < 9; ++k) {
      unsigned q = pk[k];
      int y0 = q & 255, y1 = (q >> 8) & 255, x0 = (q >> 16) & 255, x1 = q >> 24;
      v[4 * k + 0] = xb[(y0 * WW + x0) * 64 + lane];
      v[4 * k + 1] = xb[(y0 * WW + x1) * 64 + lane];
      v[4 * k + 2] = xb[(y1 * WW + x0) * 64 + lane];
      v[4 * k + 3] = xb[(y1 * WW + x1) * 64 + lane];
    }

    // (c) combine + LDS write
#pragma unroll
    for (int k = 0; k < 9; ++k) {
      float s = wj[k].x * (float)v[4 * k + 0] + wj[k].y * (float)v[4 * k + 1]
              + wj[k].z * (float)v[4 * k + 2] + wj[k].w * (float)v[4 * k + 3];
      s_A[pl * 584 + k * 64 + lane] = (_Float16)s;
    }
  }
  __syncthreads();

  // ---- phase B: [16 x 576] x [576 x 64] fp16 MFMA, wave -> 16 out-channels ----
  int r = lane & 15, g = lane >> 4;
  const _Float16* arow = s_A + r * 584 + g * 8;
  const _Float16* bp = wB + (wv * 16 + r) * 576 + g * 8;
  f32x4 accA = {0.f, 0.f, 0.f, 0.f}, accB = {0.f, 0.f, 0.f, 0.f};
#pragma unroll 3
  for (int s = 0; s < 18; s += 2) {
    f16x8 a0 = *(const f16x8*)(arow + s * 32);
    f16x8 b0 = *(const f16x8*)(bp + s * 32);
    f16x8 a1 = *(const f16x8*)(arow + s * 32 + 32);
    f16x8 b1 = *(const f16x8*)(bp + s * 32 + 32);
    accA = __builtin_amdgcn_mfma_f32_16x16x32_f16(a0, b0, accA, 0, 0, 0);
    accB = __builtin_amdgcn_mfma_f32_16x16x32_f16(a1, b1, accB, 0, 0, 0);
  }

  // ---- epilogue: bias + BN + ReLU, LDS transpose, coalesced store ----
  int o = wv * 16 + r;                                 // this lane's out channel
  float bs = bias[o] - mean[o];
  float inv = gamma[o] * rsqrtf(var[o] + BN_EPS);
  float bt = beta[o];
  __syncthreads();                                     // all s_A reads done
#pragma unroll
  for (int j = 0; j < 4; ++j) {
    int px = g * 4 + j;                                // C row = (lane>>4)*4+j
    o_lds[o * 20 + px] = fmaxf((accA[j] + accB[j] + bs) * inv + bt, 0.f);
  }
  __syncthreads();

  int oo = tid >> 2, q = tid & 3;
  float4 u = *(const float4*)&o_lds[oo * 20 + q * 4];
  *(float4*)(out + (size_t)(b * 64 + oo) * HW + hwrow + q * 4) = u;
}

extern "C" void kernel_launch(void* const* d_in, const int* in_sizes, int n_in,
                              void* d_out, int out_size, void* d_ws, size_t ws_size,
                              hipStream_t stream) {
  const float* x      = (const float*)d_in[0];
  const float* offw   = (const float*)d_in[1];
  const float* offb   = (const float*)d_in[2];
  const float* modw   = (const float*)d_in[3];
  const float* modb   = (const float*)d_in[4];
  const float* weight = (const float*)d_in[5];
  const float* bias   = (const float*)d_in[6];
  const float* gamma  = (const float*)d_in[7];
  const float* beta   = (const float*)d_in[8];
  const float* mean   = (const float*)d_in[9];
  const float* var    = (const float*)d_in[10];

  char* ws = (char*)d_ws;
  float4*    w4    = (float4*)(ws + OFF_W4);
  _Float16*  xTh   = (_Float16*)(ws + OFF_XT);
  unsigned*  xybuf = (unsigned*)(ws + OFF_XY);
  _Float16*  wB    = (_Float16*)(ws + OFF_WB);
  _Float16*  wOff  = (_Float16*)(ws + OFF_WO);

  prep_kernel<<<216, 256, 0, stream>>>(weight, offw, modw, wB, wOff);
  transpose_x_kernel<<<1152, 256, 0, stream>>>(x, xTh);
  conv_offsets_kernel<<<2304, 256, 0, stream>>>(xTh, wOff, offb, modb, w4, xybuf);
  dcn_main_kernel<<<4608, 256, 0, stream>>>(xTh, w4, xybuf, wB, bias, gamma, beta,
                                            mean, var, (float*)d_out);
}